// Round 3
// baseline (2650.499 us; speedup 1.0000x reference)
//
#include <hip/hip_runtime.h>

#define T_SEQ 2048
#define NHEAD 16
#define HD 64
#define CDIM 1024

typedef __bf16 bf16x8 __attribute__((ext_vector_type(8)));
typedef float f32x4 __attribute__((ext_vector_type(4)));

union U16x8 { uint4 u4; unsigned short s[8]; bf16x8 b; };

__device__ __forceinline__ float bf2f(unsigned short u) {
    return __uint_as_float(((unsigned int)u) << 16);
}
__device__ __forceinline__ unsigned short f2bf(float f) {
    unsigned int u = __float_as_uint(f);
    u += 0x7fffu + ((u >> 16) & 1u);   // round-to-nearest-even
    return (unsigned short)(u >> 16);
}

// 8-element loaders -> bf16x8 (packed in U16x8)
__device__ __forceinline__ U16x8 load8(const float* __restrict__ p) {
    U16x8 r;
    float4 f0 = *(const float4*)p;
    float4 f1 = *(const float4*)(p + 4);
    r.s[0] = f2bf(f0.x); r.s[1] = f2bf(f0.y); r.s[2] = f2bf(f0.z); r.s[3] = f2bf(f0.w);
    r.s[4] = f2bf(f1.x); r.s[5] = f2bf(f1.y); r.s[6] = f2bf(f1.z); r.s[7] = f2bf(f1.w);
    return r;
}
__device__ __forceinline__ U16x8 load8(const unsigned short* __restrict__ p) {
    U16x8 r;
    r.u4 = *(const uint4*)p;
    return r;
}

// ---------------------------------------------------------------------------
// GEMM core: C[64x64] = A[64xK] * B[Kx64]; A row-major [M,K] (fp32 or bf16),
// B row-major [K,N] fp32. Converts to bf16 during LDS staging.
// MFMA 16x16x32 bf16; 256 threads = 4 waves; wave w owns rows [w*16,w*16+16).
// A-frag: A[m=lane&15][k=(lane>>4)*8+j]; C/D: row=(lane>>4)*4+reg, col=lane&15.
// ---------------------------------------------------------------------------
#define LDS_STRIDE 72   // 64 + 8 pad; 144B row keeps 16B alignment

template <typename TA>
__device__ __forceinline__ void gemm_core_64x64(
    const TA* __restrict__ A, int lda,
    const float* __restrict__ B, int ldb,
    int m0, int n0, int K,
    unsigned short* As, unsigned short* Bs, f32x4 acc[4])
{
    const int tid  = threadIdx.x;
    const int wave = tid >> 6;
    const int lane = tid & 63;
    const int r    = lane & 15;
    const int quad = lane >> 4;
    const int row8 = tid >> 3;   // 0..31
    const int seg  = tid & 7;    // 0..7

    for (int kb = 0; kb < K; kb += 64) {
        __syncthreads();
        // stage A rows row8, row8+32 (8 contiguous elems per thread each)
        {
            U16x8 v0 = load8(&A[(size_t)(m0 + row8) * lda + kb + seg * 8]);
            U16x8 v1 = load8(&A[(size_t)(m0 + row8 + 32) * lda + kb + seg * 8]);
            *(uint4*)&As[row8 * LDS_STRIDE + seg * 8] = v0.u4;
            *(uint4*)&As[(row8 + 32) * LDS_STRIDE + seg * 8] = v1.u4;
        }
        // stage B transposed: Bs[n][k]
        {
            U16x8 w0 = load8(&B[(size_t)(kb + row8) * ldb + n0 + seg * 8]);
            U16x8 w1 = load8(&B[(size_t)(kb + row8 + 32) * ldb + n0 + seg * 8]);
#pragma unroll
            for (int j = 0; j < 8; ++j) {
                Bs[(seg * 8 + j) * LDS_STRIDE + row8] = w0.s[j];
                Bs[(seg * 8 + j) * LDS_STRIDE + row8 + 32] = w1.s[j];
            }
        }
        __syncthreads();
#pragma unroll
        for (int s = 0; s < 2; ++s) {
            U16x8 a;
            a.u4 = *(const uint4*)&As[(wave * 16 + r) * LDS_STRIDE + s * 32 + quad * 8];
#pragma unroll
            for (int t = 0; t < 4; ++t) {
                U16x8 b;
                b.u4 = *(const uint4*)&Bs[(t * 16 + r) * LDS_STRIDE + s * 32 + quad * 8];
                acc[t] = __builtin_amdgcn_mfma_f32_16x16x32_bf16(a.b, b.b, acc[t], 0, 0, 0);
            }
        }
    }
}

// ---------------------------------------------------------------------------
// Kernel 1: QKV = X @ W_qkv + b_qkv, scattered to Q/K/V bf16 in [B,H,T,hd]
// ---------------------------------------------------------------------------
__global__ __launch_bounds__(256) void qkv_gemm(
    const float* __restrict__ X,     // [4096, 1024] fp32
    const float* __restrict__ W,     // [1024, 3072] fp32
    const float* __restrict__ bias,  // [3072] fp32
    unsigned short* __restrict__ Qp,
    unsigned short* __restrict__ Kp,
    unsigned short* __restrict__ Vp)
{
    __shared__ unsigned short As[64 * LDS_STRIDE];
    __shared__ unsigned short Bs[64 * LDS_STRIDE];
    const int m0 = blockIdx.x * 64;
    const int n0 = blockIdx.y * 64;
    const int lane = threadIdx.x & 63;
    const int wave = threadIdx.x >> 6;
    const int r = lane & 15, quad = lane >> 4;

    f32x4 acc[4];
#pragma unroll
    for (int t = 0; t < 4; ++t) acc[t] = (f32x4){0.f, 0.f, 0.f, 0.f};

    gemm_core_64x64(X, CDIM, W, 3 * CDIM, m0, n0, CDIM, As, Bs, acc);

#pragma unroll
    for (int t = 0; t < 4; ++t) {
        const int n = n0 + t * 16 + r;
        const float bf = bias[n];
        const int which = n >> 10;          // 0=Q,1=K,2=V
        const int rc = n & 1023;
        const int h = rc >> 6, d = rc & 63;
        unsigned short* dst = which == 0 ? Qp : (which == 1 ? Kp : Vp);
#pragma unroll
        for (int i = 0; i < 4; ++i) {
            const int m = m0 + wave * 16 + quad * 4 + i;   // global row = b*T + t
            const int b = m >> 11, tt = m & 2047;
            dst[(((b * NHEAD + h) * T_SEQ) + tt) * HD + d] = f2bf(acc[t][i] + bf);
        }
    }
}

// ---------------------------------------------------------------------------
// Kernel 2: causal masked attention, one block per (b,h,q) row
// ---------------------------------------------------------------------------
__global__ __launch_bounds__(256) void attn(
    const unsigned short* __restrict__ Qp,
    const unsigned short* __restrict__ Kp,
    const unsigned short* __restrict__ Vp,
    const int* __restrict__ mask,
    unsigned short* __restrict__ Y)   // [B*T, C] bf16, c = h*64+d
{
    __shared__ float s_lds[T_SEQ];
    __shared__ float q_lds[HD];
    __shared__ float redmax[4];
    __shared__ float redsum[4];
    __shared__ float part[4 * HD];

    const int q  = blockIdx.x;
    const int bh = blockIdx.y;          // b*16 + h
    const int b  = bh >> 4;
    const int h  = bh & 15;
    const int tid = threadIdx.x;
    const size_t base = (size_t)bh * T_SEQ * HD;

    if (tid < HD) q_lds[tid] = bf2f(Qp[base + (size_t)q * HD + tid]);
    __syncthreads();

    // Phase 1: scores s[k] = (q . k_row) * 0.125, masked
    float lmax = -3.0e38f;
    for (int k = tid; k <= q; k += 256) {
        const uint4* krow = (const uint4*)&Kp[base + (size_t)k * HD];
        float acc = 0.f;
#pragma unroll
        for (int i = 0; i < 8; ++i) {     // 8 uint4 = 64 bf16 elements
            uint4 u = krow[i];
            acc = fmaf(q_lds[8 * i + 0],  __uint_as_float(u.x << 16),          acc);
            acc = fmaf(q_lds[8 * i + 1],  __uint_as_float(u.x & 0xffff0000u),  acc);
            acc = fmaf(q_lds[8 * i + 2],  __uint_as_float(u.y << 16),          acc);
            acc = fmaf(q_lds[8 * i + 3],  __uint_as_float(u.y & 0xffff0000u),  acc);
            acc = fmaf(q_lds[8 * i + 4],  __uint_as_float(u.z << 16),          acc);
            acc = fmaf(q_lds[8 * i + 5],  __uint_as_float(u.z & 0xffff0000u),  acc);
            acc = fmaf(q_lds[8 * i + 6],  __uint_as_float(u.w << 16),          acc);
            acc = fmaf(q_lds[8 * i + 7],  __uint_as_float(u.w & 0xffff0000u),  acc);
        }
        float s = (mask[b * T_SEQ + k] != 0) ? acc * 0.125f : -1.0e30f;
        s_lds[k] = s;
        lmax = fmaxf(lmax, s);
    }
#pragma unroll
    for (int o = 32; o > 0; o >>= 1) lmax = fmaxf(lmax, __shfl_xor(lmax, o));
    if ((tid & 63) == 0) redmax[tid >> 6] = lmax;
    __syncthreads();
    const float mval = fmaxf(fmaxf(redmax[0], redmax[1]), fmaxf(redmax[2], redmax[3]));

    // Phase 2: exp + sum
    float lsum = 0.f;
    for (int k = tid; k <= q; k += 256) {
        float e = __expf(s_lds[k] - mval);
        s_lds[k] = e;
        lsum += e;
    }
#pragma unroll
    for (int o = 32; o > 0; o >>= 1) lsum += __shfl_xor(lsum, o);
    if ((tid & 63) == 0) redsum[tid >> 6] = lsum;
    __syncthreads();
    const float inv = 1.0f / (redsum[0] + redsum[1] + redsum[2] + redsum[3]);

    // Phase 3: O[d] = sum_k p[k] * V[k][d]
    const int d = tid & 63, c = tid >> 6;
    float acc = 0.f;
    for (int k = c; k <= q; k += 4)
        acc = fmaf(s_lds[k], bf2f(Vp[base + (size_t)k * HD + d]), acc);
    part[c * HD + d] = acc;
    __syncthreads();
    if (tid < HD) {
        float v = (part[tid] + part[HD + tid] + part[2 * HD + tid] + part[3 * HD + tid]) * inv;
        Y[((size_t)(b * T_SEQ + q)) * CDIM + h * HD + tid] = f2bf(v);
    }
}

// ---------------------------------------------------------------------------
// Kernel 3: out = Y @ W_proj + b_proj   ([4096,1024] x [1024,1024]) -> fp32
// ---------------------------------------------------------------------------
__global__ __launch_bounds__(256) void proj_gemm(
    const unsigned short* __restrict__ Yin,   // [4096, 1024] bf16
    const float* __restrict__ W,              // [1024, 1024] fp32
    const float* __restrict__ bias,           // [1024] fp32
    float* __restrict__ out)                  // [4096, 1024] fp32
{
    __shared__ unsigned short As[64 * LDS_STRIDE];
    __shared__ unsigned short Bs[64 * LDS_STRIDE];
    const int m0 = blockIdx.x * 64;
    const int n0 = blockIdx.y * 64;
    const int lane = threadIdx.x & 63;
    const int wave = threadIdx.x >> 6;
    const int r = lane & 15, quad = lane >> 4;

    f32x4 acc[4];
#pragma unroll
    for (int t = 0; t < 4; ++t) acc[t] = (f32x4){0.f, 0.f, 0.f, 0.f};

    gemm_core_64x64(Yin, CDIM, W, CDIM, m0, n0, CDIM, As, Bs, acc);

#pragma unroll
    for (int t = 0; t < 4; ++t) {
        const int n = n0 + t * 16 + r;
        const float bf = bias[n];
#pragma unroll
        for (int i = 0; i < 4; ++i) {
            const int m = m0 + wave * 16 + quad * 4 + i;
            out[(size_t)m * CDIM + n] = acc[t][i] + bf;
        }
    }
}

// ---------------------------------------------------------------------------
extern "C" void kernel_launch(void* const* d_in, const int* in_sizes, int n_in,
                              void* d_out, int out_size, void* d_ws, size_t ws_size,
                              hipStream_t stream)
{
    const float* X     = (const float*)d_in[0];
    const int*   mask  = (const int*)d_in[1];
    const float* Wqkv  = (const float*)d_in[2];
    const float* bqkv  = (const float*)d_in[3];
    const float* Wproj = (const float*)d_in[4];
    const float* bproj = (const float*)d_in[5];
    float* out = (float*)d_out;

    const size_t per = (size_t)2 * NHEAD * T_SEQ * HD;   // 4,194,304 elems
    unsigned short* Qp = (unsigned short*)d_ws;
    unsigned short* Kp = Qp + per;
    unsigned short* Vp = Kp + per;
    unsigned short* Yp = Vp + per;

    qkv_gemm<<<dim3(64, 48), 256, 0, stream>>>(X, Wqkv, bqkv, Qp, Kp, Vp);
    attn<<<dim3(T_SEQ, 2 * NHEAD), 256, 0, stream>>>(Qp, Kp, Vp, mask, Yp);
    proj_gemm<<<dim3(64, 16), 256, 0, stream>>>(Yp, Wproj, bproj, out);
}

// Round 4
// 372.692 us; speedup vs baseline: 7.1118x; 7.1118x over previous
//
#include <hip/hip_runtime.h>

#define T_SEQ 2048
#define NHEAD 16
#define HD 64
#define CDIM 1024

typedef __bf16 bf16x8 __attribute__((ext_vector_type(8)));
typedef float f32x4 __attribute__((ext_vector_type(4)));

union U16x8 { uint4 u4; unsigned short s[8]; bf16x8 b; };

__device__ __forceinline__ float bf2f(unsigned short u) {
    return __uint_as_float(((unsigned int)u) << 16);
}
__device__ __forceinline__ unsigned short f2bf(float f) {
    unsigned int u = __float_as_uint(f);
    u += 0x7fffu + ((u >> 16) & 1u);   // round-to-nearest-even
    return (unsigned short)(u >> 16);
}

// 8-element loaders -> bf16x8 (packed in U16x8)
__device__ __forceinline__ U16x8 load8(const float* __restrict__ p) {
    U16x8 r;
    float4 f0 = *(const float4*)p;
    float4 f1 = *(const float4*)(p + 4);
    r.s[0] = f2bf(f0.x); r.s[1] = f2bf(f0.y); r.s[2] = f2bf(f0.z); r.s[3] = f2bf(f0.w);
    r.s[4] = f2bf(f1.x); r.s[5] = f2bf(f1.y); r.s[6] = f2bf(f1.z); r.s[7] = f2bf(f1.w);
    return r;
}
__device__ __forceinline__ U16x8 load8(const unsigned short* __restrict__ p) {
    U16x8 r;
    r.u4 = *(const uint4*)p;
    return r;
}

// ---------------------------------------------------------------------------
// GEMM core: C[64x64] = A[64xK] * B[Kx64]; A row-major [M,K] (fp32 or bf16),
// B row-major [K,N] fp32. Converts to bf16 during LDS staging.
// MFMA 16x16x32 bf16; 256 threads = 4 waves; wave w owns rows [w*16,w*16+16).
// A-frag: A[m=lane&15][k=(lane>>4)*8+j]; C/D: row=(lane>>4)*4+reg, col=lane&15.
// ---------------------------------------------------------------------------
#define LDS_STRIDE 72   // 64 + 8 pad; 144B row keeps 16B alignment

template <typename TA>
__device__ __forceinline__ void gemm_core_64x64(
    const TA* __restrict__ A, int lda,
    const float* __restrict__ B, int ldb,
    int m0, int n0, int K,
    unsigned short* As, unsigned short* Bs, f32x4 acc[4])
{
    const int tid  = threadIdx.x;
    const int wave = tid >> 6;
    const int lane = tid & 63;
    const int r    = lane & 15;
    const int quad = lane >> 4;
    const int row8 = tid >> 3;   // 0..31
    const int seg  = tid & 7;    // 0..7

    for (int kb = 0; kb < K; kb += 64) {
        __syncthreads();
        {
            U16x8 v0 = load8(&A[(size_t)(m0 + row8) * lda + kb + seg * 8]);
            U16x8 v1 = load8(&A[(size_t)(m0 + row8 + 32) * lda + kb + seg * 8]);
            *(uint4*)&As[row8 * LDS_STRIDE + seg * 8] = v0.u4;
            *(uint4*)&As[(row8 + 32) * LDS_STRIDE + seg * 8] = v1.u4;
        }
        {
            U16x8 w0 = load8(&B[(size_t)(kb + row8) * ldb + n0 + seg * 8]);
            U16x8 w1 = load8(&B[(size_t)(kb + row8 + 32) * ldb + n0 + seg * 8]);
#pragma unroll
            for (int j = 0; j < 8; ++j) {
                Bs[(seg * 8 + j) * LDS_STRIDE + row8] = w0.s[j];
                Bs[(seg * 8 + j) * LDS_STRIDE + row8 + 32] = w1.s[j];
            }
        }
        __syncthreads();
#pragma unroll
        for (int s = 0; s < 2; ++s) {
            U16x8 a;
            a.u4 = *(const uint4*)&As[(wave * 16 + r) * LDS_STRIDE + s * 32 + quad * 8];
#pragma unroll
            for (int t = 0; t < 4; ++t) {
                U16x8 b;
                b.u4 = *(const uint4*)&Bs[(t * 16 + r) * LDS_STRIDE + s * 32 + quad * 8];
                acc[t] = __builtin_amdgcn_mfma_f32_16x16x32_bf16(a.b, b.b, acc[t], 0, 0, 0);
            }
        }
    }
}

// ---------------------------------------------------------------------------
// Kernel 1: QKV = X @ W_qkv + b_qkv; Q,K -> [B,H,T,hd] bf16; V -> [B,H,hd,T]
// ---------------------------------------------------------------------------
__global__ __launch_bounds__(256) void qkv_gemm(
    const float* __restrict__ X,     // [4096, 1024] fp32
    const float* __restrict__ W,     // [1024, 3072] fp32
    const float* __restrict__ bias,  // [3072] fp32
    unsigned short* __restrict__ Qp,
    unsigned short* __restrict__ Kp,
    unsigned short* __restrict__ Vtp)
{
    __shared__ unsigned short As[64 * LDS_STRIDE];
    __shared__ unsigned short Bs[64 * LDS_STRIDE];
    const int m0 = blockIdx.x * 64;
    const int n0 = blockIdx.y * 64;
    const int lane = threadIdx.x & 63;
    const int wave = threadIdx.x >> 6;
    const int r = lane & 15, quad = lane >> 4;

    f32x4 acc[4];
#pragma unroll
    for (int t = 0; t < 4; ++t) acc[t] = (f32x4){0.f, 0.f, 0.f, 0.f};

    gemm_core_64x64(X, CDIM, W, 3 * CDIM, m0, n0, CDIM, As, Bs, acc);

#pragma unroll
    for (int t = 0; t < 4; ++t) {
        const int n = n0 + t * 16 + r;
        const float bf = bias[n];
        const int which = n >> 10;          // 0=Q,1=K,2=V
        const int rc = n & 1023;
        const int h = rc >> 6, d = rc & 63;
#pragma unroll
        for (int i = 0; i < 4; ++i) {
            const int m = m0 + wave * 16 + quad * 4 + i;   // global row = b*T + t
            const int b = m >> 11, tt = m & 2047;
            const unsigned short val = f2bf(acc[t][i] + bf);
            if (which == 0)
                Qp[(((b * NHEAD + h) * T_SEQ) + tt) * HD + d] = val;
            else if (which == 1)
                Kp[(((b * NHEAD + h) * T_SEQ) + tt) * HD + d] = val;
            else
                Vtp[(((b * NHEAD + h) * HD) + d) * T_SEQ + tt] = val;   // transposed
        }
    }
}

// ---------------------------------------------------------------------------
// Kernel 2: MFMA flash attention. Block = (b,h) x 64-row Q-tile; 4 waves x 16
// q-rows. K-tile loop with online softmax. P round-trips LDS (C-layout ->
// A-layout, m120 pattern). V is pre-transposed so PV B-frags are contiguous.
// ---------------------------------------------------------------------------
#define ATT_STRIDE 72

__global__ __launch_bounds__(256) void flash_attn(
    const unsigned short* __restrict__ Qp,   // [BH, T, 64]
    const unsigned short* __restrict__ Kp,   // [BH, T, 64]
    const unsigned short* __restrict__ Vtp,  // [BH, 64, T]
    const int* __restrict__ mask,            // [B, T]
    unsigned short* __restrict__ Y)          // [B*T, 1024] bf16
{
    __shared__ unsigned short Ks[64 * ATT_STRIDE];
    __shared__ unsigned short Vs[64 * ATT_STRIDE];
    __shared__ unsigned short Ps[64 * ATT_STRIDE];
    __shared__ int mask_s[64];

    const int qt = gridDim.x - 1 - blockIdx.x;   // heavy tiles launch first
    const int bh = blockIdx.y;
    const int b = bh >> 4, h = bh & 15;
    const int tid = threadIdx.x;
    const int w = tid >> 6, lane = tid & 63;
    const int ln = lane & 15, quad = lane >> 4;
    const int row8 = tid >> 3, seg = tid & 7;
    const size_t base = (size_t)bh * T_SEQ * HD;
    const int q0 = qt * 64;

    // Q A-fragments (held in registers for the whole block)
    U16x8 qf[2];
    {
        const unsigned short* qrow = &Qp[base + (size_t)(q0 + w * 16 + ln) * HD];
        qf[0].u4 = *(const uint4*)&qrow[quad * 8];
        qf[1].u4 = *(const uint4*)&qrow[32 + quad * 8];
    }

    f32x4 o[4];
#pragma unroll
    for (int n = 0; n < 4; ++n) o[n] = (f32x4){0.f, 0.f, 0.f, 0.f};
    float m_i[4] = {-3.0e38f, -3.0e38f, -3.0e38f, -3.0e38f};
    float l_i[4] = {0.f, 0.f, 0.f, 0.f};

    for (int j = 0; j <= qt; ++j) {
        __syncthreads();
        // stage K-tile [key][hd] and Vt-tile [hd][key]
        {
            const unsigned short* kp0 = &Kp[base + (size_t)(j * 64 + row8) * HD + seg * 8];
            uint4 k0 = *(const uint4*)kp0;
            uint4 k1 = *(const uint4*)(kp0 + 32 * HD);
            *(uint4*)&Ks[row8 * ATT_STRIDE + seg * 8] = k0;
            *(uint4*)&Ks[(row8 + 32) * ATT_STRIDE + seg * 8] = k1;
            const unsigned short* vp0 = &Vtp[base + (size_t)row8 * T_SEQ + j * 64 + seg * 8];
            uint4 v0 = *(const uint4*)vp0;
            uint4 v1 = *(const uint4*)(vp0 + 32 * T_SEQ);
            *(uint4*)&Vs[row8 * ATT_STRIDE + seg * 8] = v0;
            *(uint4*)&Vs[(row8 + 32) * ATT_STRIDE + seg * 8] = v1;
            if (tid < 64) mask_s[tid] = mask[b * T_SEQ + j * 64 + tid];
        }
        __syncthreads();

        const bool diag = (j == qt);

        // S = Q K^T  (frag t covers keys t*16..t*16+15)
        f32x4 sc[4];
#pragma unroll
        for (int t = 0; t < 4; ++t) sc[t] = (f32x4){0.f, 0.f, 0.f, 0.f};
#pragma unroll
        for (int t = 0; t < 4; ++t) {
            if (diag && t > w) continue;   // fully-masked frag on diagonal tile
#pragma unroll
            for (int s = 0; s < 2; ++s) {
                U16x8 kb;
                kb.u4 = *(const uint4*)&Ks[(t * 16 + ln) * ATT_STRIDE + s * 32 + quad * 8];
                sc[t] = __builtin_amdgcn_mfma_f32_16x16x32_bf16(qf[s].b, kb.b, sc[t], 0, 0, 0);
            }
        }

        // mask + scale + row max
        float rm[4] = {-3.0e38f, -3.0e38f, -3.0e38f, -3.0e38f};
#pragma unroll
        for (int t = 0; t < 4; ++t) {
            const int pad = mask_s[t * 16 + ln];
            const bool allmask = diag && (t > w);
            const bool edge = diag && (t == w);
#pragma unroll
            for (int i = 0; i < 4; ++i) {
                float v = sc[t][i] * 0.125f;
                if (pad == 0 || allmask || (edge && ln > quad * 4 + i)) v = -1.0e30f;
                sc[t][i] = v;
                rm[i] = fmaxf(rm[i], v);
            }
        }
#pragma unroll
        for (int i = 0; i < 4; ++i) {
            rm[i] = fmaxf(rm[i], __shfl_xor(rm[i], 1));
            rm[i] = fmaxf(rm[i], __shfl_xor(rm[i], 2));
            rm[i] = fmaxf(rm[i], __shfl_xor(rm[i], 4));
            rm[i] = fmaxf(rm[i], __shfl_xor(rm[i], 8));
        }

        float alpha[4], rs[4] = {0.f, 0.f, 0.f, 0.f};
#pragma unroll
        for (int i = 0; i < 4; ++i) {
            const float nm = fmaxf(m_i[i], rm[i]);
            alpha[i] = __expf(m_i[i] - nm);
            m_i[i] = nm;
        }
#pragma unroll
        for (int t = 0; t < 4; ++t)
#pragma unroll
            for (int i = 0; i < 4; ++i) {
                const float p = __expf(sc[t][i] - m_i[i]);
                sc[t][i] = p;
                rs[i] += p;
            }
#pragma unroll
        for (int i = 0; i < 4; ++i) {
            rs[i] += __shfl_xor(rs[i], 1);
            rs[i] += __shfl_xor(rs[i], 2);
            rs[i] += __shfl_xor(rs[i], 4);
            rs[i] += __shfl_xor(rs[i], 8);
            l_i[i] = l_i[i] * alpha[i] + rs[i];
        }
#pragma unroll
        for (int n = 0; n < 4; ++n)
#pragma unroll
            for (int i = 0; i < 4; ++i) o[n][i] *= alpha[i];

        // P (C-layout) -> LDS -> A-layout fragments (wave-private region)
#pragma unroll
        for (int t = 0; t < 4; ++t)
#pragma unroll
            for (int i = 0; i < 4; ++i)
                Ps[(w * 16 + quad * 4 + i) * ATT_STRIDE + t * 16 + ln] = f2bf(sc[t][i]);

        U16x8 pa[2];
        pa[0].u4 = *(const uint4*)&Ps[(w * 16 + ln) * ATT_STRIDE + quad * 8];
        pa[1].u4 = *(const uint4*)&Ps[(w * 16 + ln) * ATT_STRIDE + 32 + quad * 8];

        // O += P V   (frag n covers hd dims n*16..n*16+15)
#pragma unroll
        for (int n = 0; n < 4; ++n)
#pragma unroll
            for (int s = 0; s < 2; ++s) {
                U16x8 vb;
                vb.u4 = *(const uint4*)&Vs[(n * 16 + ln) * ATT_STRIDE + s * 32 + quad * 8];
                o[n] = __builtin_amdgcn_mfma_f32_16x16x32_bf16(pa[s].b, vb.b, o[n], 0, 0, 0);
            }
    }

    // epilogue: O / l -> Y
#pragma unroll
    for (int i = 0; i < 4; ++i) {
        const float inv = 1.0f / l_i[i];
        const size_t row = (size_t)(b * T_SEQ + q0 + w * 16 + quad * 4 + i);
#pragma unroll
        for (int n = 0; n < 4; ++n)
            Y[row * CDIM + h * HD + n * 16 + ln] = f2bf(o[n][i] * inv);
    }
}

// ---------------------------------------------------------------------------
// Kernel 3: out = Y @ W_proj + b_proj   ([4096,1024] x [1024,1024]) -> fp32
// ---------------------------------------------------------------------------
__global__ __launch_bounds__(256) void proj_gemm(
    const unsigned short* __restrict__ Yin,   // [4096, 1024] bf16
    const float* __restrict__ W,              // [1024, 1024] fp32
    const float* __restrict__ bias,           // [1024] fp32
    float* __restrict__ out)                  // [4096, 1024] fp32
{
    __shared__ unsigned short As[64 * LDS_STRIDE];
    __shared__ unsigned short Bs[64 * LDS_STRIDE];
    const int m0 = blockIdx.x * 64;
    const int n0 = blockIdx.y * 64;
    const int lane = threadIdx.x & 63;
    const int wave = threadIdx.x >> 6;
    const int r = lane & 15, quad = lane >> 4;

    f32x4 acc[4];
#pragma unroll
    for (int t = 0; t < 4; ++t) acc[t] = (f32x4){0.f, 0.f, 0.f, 0.f};

    gemm_core_64x64(Yin, CDIM, W, CDIM, m0, n0, CDIM, As, Bs, acc);

#pragma unroll
    for (int t = 0; t < 4; ++t) {
        const int n = n0 + t * 16 + r;
        const float bf = bias[n];
#pragma unroll
        for (int i = 0; i < 4; ++i) {
            const int m = m0 + wave * 16 + quad * 4 + i;
            out[(size_t)m * CDIM + n] = acc[t][i] + bf;
        }
    }
}

// ---------------------------------------------------------------------------
extern "C" void kernel_launch(void* const* d_in, const int* in_sizes, int n_in,
                              void* d_out, int out_size, void* d_ws, size_t ws_size,
                              hipStream_t stream)
{
    const float* X     = (const float*)d_in[0];
    const int*   mask  = (const int*)d_in[1];
    const float* Wqkv  = (const float*)d_in[2];
    const float* bqkv  = (const float*)d_in[3];
    const float* Wproj = (const float*)d_in[4];
    const float* bproj = (const float*)d_in[5];
    float* out = (float*)d_out;

    const size_t per = (size_t)2 * NHEAD * T_SEQ * HD;   // 4,194,304 elems
    unsigned short* Qp  = (unsigned short*)d_ws;
    unsigned short* Kp  = Qp + per;
    unsigned short* Vtp = Kp + per;
    unsigned short* Yp  = Vtp + per;

    qkv_gemm<<<dim3(64, 48), 256, 0, stream>>>(X, Wqkv, bqkv, Qp, Kp, Vtp);
    flash_attn<<<dim3(T_SEQ / 64, 2 * NHEAD), 256, 0, stream>>>(Qp, Kp, Vtp, mask, Yp);
    proj_gemm<<<dim3(64, 16), 256, 0, stream>>>(Yp, Wproj, bproj, out);
}

// Round 5
// 292.792 us; speedup vs baseline: 9.0525x; 1.2729x over previous
//
#include <hip/hip_runtime.h>

#define T_SEQ 2048
#define NHEAD 16
#define HD 64
#define CDIM 1024

typedef __bf16 bf16x8 __attribute__((ext_vector_type(8)));
typedef float f32x4 __attribute__((ext_vector_type(4)));

union U16x8 { uint4 u4; unsigned short s[8]; bf16x8 b; };

__device__ __forceinline__ float bf2f(unsigned short u) {
    return __uint_as_float(((unsigned int)u) << 16);
}
__device__ __forceinline__ unsigned short f2bf(float f) {
    unsigned int u = __float_as_uint(f);
    u += 0x7fffu + ((u >> 16) & 1u);   // round-to-nearest-even
    return (unsigned short)(u >> 16);
}
__device__ __forceinline__ U16x8 load8f(const float* __restrict__ p) {
    U16x8 r;
    float4 f0 = *(const float4*)p;
    float4 f1 = *(const float4*)(p + 4);
    r.s[0] = f2bf(f0.x); r.s[1] = f2bf(f0.y); r.s[2] = f2bf(f0.z); r.s[3] = f2bf(f0.w);
    r.s[4] = f2bf(f1.x); r.s[5] = f2bf(f1.y); r.s[6] = f2bf(f1.z); r.s[7] = f2bf(f1.w);
    return r;
}

// async global->LDS, 16 B per lane; LDS dest = wave-uniform base + lane*16
__device__ __forceinline__ void async_copy16(const unsigned short* g, unsigned short* l) {
    __builtin_amdgcn_global_load_lds(
        (const __attribute__((address_space(1))) unsigned int*)g,
        (__attribute__((address_space(3))) unsigned int*)l, 16, 0, 0);
}

// ---------------------------------------------------------------------------
// Conversion pass
// ---------------------------------------------------------------------------
__global__ __launch_bounds__(256) void conv_bf16(
    const float* __restrict__ in, unsigned short* __restrict__ out, int n)
{
    const int i = (blockIdx.x * 256 + threadIdx.x) * 8;
    if (i < n) {
        U16x8 o = load8f(&in[i]);
        *(uint4*)&out[i] = o.u4;
    }
}

// in: [R,C] fp32 -> out: [C,R] bf16.  R,C multiples of 64.
__global__ __launch_bounds__(256) void transpose_conv(
    const float* __restrict__ in, unsigned short* __restrict__ out, int R, int C)
{
    __shared__ float tile[64][65];
    const int r0 = blockIdx.x * 64;
    const int c0 = blockIdx.y * 64;
    const int tid = threadIdx.x;
    const int rr = tid >> 4;
    const int cc = (tid & 15) * 4;
#pragma unroll
    for (int p = 0; p < 4; ++p) {
        float4 v = *(const float4*)&in[(size_t)(r0 + p * 16 + rr) * C + c0 + cc];
        tile[p * 16 + rr][cc] = v.x;
        tile[p * 16 + rr][cc + 1] = v.y;
        tile[p * 16 + rr][cc + 2] = v.z;
        tile[p * 16 + rr][cc + 3] = v.w;
    }
    __syncthreads();
    const int n = tid >> 2;
    const int s = (tid & 3) * 8;
#pragma unroll
    for (int p = 0; p < 2; ++p) {
        const int k = s + p * 32;
        U16x8 o;
#pragma unroll
        for (int j = 0; j < 8; ++j) o.s[j] = f2bf(tile[k + j][n]);
        *(uint4*)&out[(size_t)(c0 + n) * R + r0 + k] = o.u4;
    }
}

// ---------------------------------------------------------------------------
// m97-style GEMM core: C[128x128] = A[M,K](bf16 rm) * Bt[N,K](bf16 rm)^T
// 256 threads = 4 waves in 2x2; BK=64; global_load_lds 16B staging; 4x4 acc.
// ---------------------------------------------------------------------------
__device__ __forceinline__ void gemm128_core(
    const unsigned short* __restrict__ A,
    const unsigned short* __restrict__ Bt,
    int K, int m0, int n0,
    unsigned short* As, unsigned short* Bs, f32x4 acc[4][4])
{
    const int tid = threadIdx.x;
    const int w = tid >> 6, lane = tid & 63;
    const int ln = lane & 15, quad = lane >> 4;
    const int wm = w >> 1, wn = w & 1;
    const int lr = lane >> 3;        // 0..7
    const int lc = (lane & 7) * 8;   // col start (elems)

    for (int kb = 0; kb < K; kb += 64) {
        __syncthreads();
#pragma unroll
        for (int i = 0; i < 4; ++i) {
            async_copy16(&A[(size_t)(m0 + w * 32 + i * 8 + lr) * K + kb + lc],
                         &As[(w * 32 + i * 8) * 64]);
            async_copy16(&Bt[(size_t)(n0 + w * 32 + i * 8 + lr) * K + kb + lc],
                         &Bs[(w * 32 + i * 8) * 64]);
        }
        __syncthreads();
#pragma unroll
        for (int kk = 0; kk < 2; ++kk) {
            U16x8 af[4], bff[4];
#pragma unroll
            for (int i = 0; i < 4; ++i)
                af[i].u4 = *(const uint4*)&As[(wm * 64 + i * 16 + ln) * 64 + kk * 32 + quad * 8];
#pragma unroll
            for (int j = 0; j < 4; ++j)
                bff[j].u4 = *(const uint4*)&Bs[(wn * 64 + j * 16 + ln) * 64 + kk * 32 + quad * 8];
#pragma unroll
            for (int i = 0; i < 4; ++i)
#pragma unroll
                for (int j = 0; j < 4; ++j)
                    acc[i][j] = __builtin_amdgcn_mfma_f32_16x16x32_bf16(af[i].b, bff[j].b, acc[i][j], 0, 0, 0);
        }
    }
}

// ---------------------------------------------------------------------------
// Kernel: QKV GEMM + scatter.  Q,K -> [B,H,T,hd]; V -> [B,H,hd,T]
// ---------------------------------------------------------------------------
__global__ __launch_bounds__(256) void qkv_gemm(
    const unsigned short* __restrict__ Xb,    // [4096,1024] bf16
    const unsigned short* __restrict__ Wt,    // [3072,1024] bf16 (W^T)
    const float* __restrict__ bias,           // [3072]
    unsigned short* __restrict__ Qp,
    unsigned short* __restrict__ Kp,
    unsigned short* __restrict__ Vtp)
{
    __shared__ unsigned short As[128 * 64];
    __shared__ unsigned short Bs[128 * 64];
    const int m0 = blockIdx.x * 128;
    const int n0 = blockIdx.y * 128;

    f32x4 acc[4][4];
#pragma unroll
    for (int i = 0; i < 4; ++i)
#pragma unroll
        for (int j = 0; j < 4; ++j) acc[i][j] = (f32x4){0.f, 0.f, 0.f, 0.f};

    gemm128_core(Xb, Wt, CDIM, m0, n0, As, Bs, acc);

    const int tid = threadIdx.x;
    const int w = tid >> 6, lane = tid & 63;
    const int ln = lane & 15, quad = lane >> 4;
    const int wm = w >> 1, wn = w & 1;

#pragma unroll
    for (int j = 0; j < 4; ++j) {
        const int n = n0 + wn * 64 + j * 16 + ln;
        const float bv = bias[n];
        const int which = n >> 10;
        const int h = (n >> 6) & 15, d = n & 63;
#pragma unroll
        for (int i = 0; i < 4; ++i)
#pragma unroll
            for (int r = 0; r < 4; ++r) {
                const int m = m0 + wm * 64 + i * 16 + quad * 4 + r;
                const int b = m >> 11, tt = m & 2047;
                const unsigned short val = f2bf(acc[i][j][r] + bv);
                if (which == 0)
                    Qp[(((b * NHEAD + h) * T_SEQ) + tt) * HD + d] = val;
                else if (which == 1)
                    Kp[(((b * NHEAD + h) * T_SEQ) + tt) * HD + d] = val;
                else
                    Vtp[(((b * NHEAD + h) * HD) + d) * T_SEQ + tt] = val;
            }
    }
}

// ---------------------------------------------------------------------------
// Kernel: proj GEMM -> fp32 out
// ---------------------------------------------------------------------------
__global__ __launch_bounds__(256) void proj_gemm(
    const unsigned short* __restrict__ Yin,   // [4096,1024] bf16
    const unsigned short* __restrict__ Wt,    // [1024,1024] bf16 (W^T)
    const float* __restrict__ bias,           // [1024]
    float* __restrict__ out)                  // [4096,1024] fp32
{
    __shared__ unsigned short As[128 * 64];
    __shared__ unsigned short Bs[128 * 64];
    const int m0 = blockIdx.x * 128;
    const int n0 = blockIdx.y * 128;

    f32x4 acc[4][4];
#pragma unroll
    for (int i = 0; i < 4; ++i)
#pragma unroll
        for (int j = 0; j < 4; ++j) acc[i][j] = (f32x4){0.f, 0.f, 0.f, 0.f};

    gemm128_core(Yin, Wt, CDIM, m0, n0, As, Bs, acc);

    const int tid = threadIdx.x;
    const int w = tid >> 6, lane = tid & 63;
    const int ln = lane & 15, quad = lane >> 4;
    const int wm = w >> 1, wn = w & 1;

#pragma unroll
    for (int j = 0; j < 4; ++j) {
        const int n = n0 + wn * 64 + j * 16 + ln;
        const float bv = bias[n];
#pragma unroll
        for (int i = 0; i < 4; ++i)
#pragma unroll
            for (int r = 0; r < 4; ++r) {
                const int m = m0 + wm * 64 + i * 16 + quad * 4 + r;
                out[(size_t)m * CDIM + n] = acc[i][j][r] + bv;
            }
    }
}

// ---------------------------------------------------------------------------
// MFMA flash attention (unchanged from round 4)
// ---------------------------------------------------------------------------
#define ATT_STRIDE 72

__global__ __launch_bounds__(256) void flash_attn(
    const unsigned short* __restrict__ Qp,   // [BH, T, 64]
    const unsigned short* __restrict__ Kp,   // [BH, T, 64]
    const unsigned short* __restrict__ Vtp,  // [BH, 64, T]
    const int* __restrict__ mask,            // [B, T]
    unsigned short* __restrict__ Y)          // [B*T, 1024] bf16
{
    __shared__ unsigned short Ks[64 * ATT_STRIDE];
    __shared__ unsigned short Vs[64 * ATT_STRIDE];
    __shared__ unsigned short Ps[64 * ATT_STRIDE];
    __shared__ int mask_s[64];

    const int qt = gridDim.x - 1 - blockIdx.x;
    const int bh = blockIdx.y;
    const int b = bh >> 4, h = bh & 15;
    const int tid = threadIdx.x;
    const int w = tid >> 6, lane = tid & 63;
    const int ln = lane & 15, quad = lane >> 4;
    const int row8 = tid >> 3, seg = tid & 7;
    const size_t base = (size_t)bh * T_SEQ * HD;
    const int q0 = qt * 64;

    U16x8 qf[2];
    {
        const unsigned short* qrow = &Qp[base + (size_t)(q0 + w * 16 + ln) * HD];
        qf[0].u4 = *(const uint4*)&qrow[quad * 8];
        qf[1].u4 = *(const uint4*)&qrow[32 + quad * 8];
    }

    f32x4 o[4];
#pragma unroll
    for (int n = 0; n < 4; ++n) o[n] = (f32x4){0.f, 0.f, 0.f, 0.f};
    float m_i[4] = {-3.0e38f, -3.0e38f, -3.0e38f, -3.0e38f};
    float l_i[4] = {0.f, 0.f, 0.f, 0.f};

    for (int j = 0; j <= qt; ++j) {
        __syncthreads();
        {
            const unsigned short* kp0 = &Kp[base + (size_t)(j * 64 + row8) * HD + seg * 8];
            uint4 k0 = *(const uint4*)kp0;
            uint4 k1 = *(const uint4*)(kp0 + 32 * HD);
            *(uint4*)&Ks[row8 * ATT_STRIDE + seg * 8] = k0;
            *(uint4*)&Ks[(row8 + 32) * ATT_STRIDE + seg * 8] = k1;
            const unsigned short* vp0 = &Vtp[base + (size_t)row8 * T_SEQ + j * 64 + seg * 8];
            uint4 v0 = *(const uint4*)vp0;
            uint4 v1 = *(const uint4*)(vp0 + 32 * T_SEQ);
            *(uint4*)&Vs[row8 * ATT_STRIDE + seg * 8] = v0;
            *(uint4*)&Vs[(row8 + 32) * ATT_STRIDE + seg * 8] = v1;
            if (tid < 64) mask_s[tid] = mask[b * T_SEQ + j * 64 + tid];
        }
        __syncthreads();

        const bool diag = (j == qt);

        f32x4 sc[4];
#pragma unroll
        for (int t = 0; t < 4; ++t) sc[t] = (f32x4){0.f, 0.f, 0.f, 0.f};
#pragma unroll
        for (int t = 0; t < 4; ++t) {
            if (diag && t > w) continue;
#pragma unroll
            for (int s = 0; s < 2; ++s) {
                U16x8 kb;
                kb.u4 = *(const uint4*)&Ks[(t * 16 + ln) * ATT_STRIDE + s * 32 + quad * 8];
                sc[t] = __builtin_amdgcn_mfma_f32_16x16x32_bf16(qf[s].b, kb.b, sc[t], 0, 0, 0);
            }
        }

        float rm[4] = {-3.0e38f, -3.0e38f, -3.0e38f, -3.0e38f};
#pragma unroll
        for (int t = 0; t < 4; ++t) {
            const int pad = mask_s[t * 16 + ln];
            const bool allmask = diag && (t > w);
            const bool edge = diag && (t == w);
#pragma unroll
            for (int i = 0; i < 4; ++i) {
                float v = sc[t][i] * 0.125f;
                if (pad == 0 || allmask || (edge && ln > quad * 4 + i)) v = -1.0e30f;
                sc[t][i] = v;
                rm[i] = fmaxf(rm[i], v);
            }
        }
#pragma unroll
        for (int i = 0; i < 4; ++i) {
            rm[i] = fmaxf(rm[i], __shfl_xor(rm[i], 1));
            rm[i] = fmaxf(rm[i], __shfl_xor(rm[i], 2));
            rm[i] = fmaxf(rm[i], __shfl_xor(rm[i], 4));
            rm[i] = fmaxf(rm[i], __shfl_xor(rm[i], 8));
        }

        float alpha[4], rs[4] = {0.f, 0.f, 0.f, 0.f};
#pragma unroll
        for (int i = 0; i < 4; ++i) {
            const float nm = fmaxf(m_i[i], rm[i]);
            alpha[i] = __expf(m_i[i] - nm);
            m_i[i] = nm;
        }
#pragma unroll
        for (int t = 0; t < 4; ++t)
#pragma unroll
            for (int i = 0; i < 4; ++i) {
                const float p = __expf(sc[t][i] - m_i[i]);
                sc[t][i] = p;
                rs[i] += p;
            }
#pragma unroll
        for (int i = 0; i < 4; ++i) {
            rs[i] += __shfl_xor(rs[i], 1);
            rs[i] += __shfl_xor(rs[i], 2);
            rs[i] += __shfl_xor(rs[i], 4);
            rs[i] += __shfl_xor(rs[i], 8);
            l_i[i] = l_i[i] * alpha[i] + rs[i];
        }
#pragma unroll
        for (int n = 0; n < 4; ++n)
#pragma unroll
            for (int i = 0; i < 4; ++i) o[n][i] *= alpha[i];

#pragma unroll
        for (int t = 0; t < 4; ++t)
#pragma unroll
            for (int i = 0; i < 4; ++i)
                Ps[(w * 16 + quad * 4 + i) * ATT_STRIDE + t * 16 + ln] = f2bf(sc[t][i]);

        U16x8 pa[2];
        pa[0].u4 = *(const uint4*)&Ps[(w * 16 + ln) * ATT_STRIDE + quad * 8];
        pa[1].u4 = *(const uint4*)&Ps[(w * 16 + ln) * ATT_STRIDE + 32 + quad * 8];

#pragma unroll
        for (int n = 0; n < 4; ++n)
#pragma unroll
            for (int s = 0; s < 2; ++s) {
                U16x8 vb;
                vb.u4 = *(const uint4*)&Vs[(n * 16 + ln) * ATT_STRIDE + s * 32 + quad * 8];
                o[n] = __builtin_amdgcn_mfma_f32_16x16x32_bf16(pa[s].b, vb.b, o[n], 0, 0, 0);
            }
    }

#pragma unroll
    for (int i = 0; i < 4; ++i) {
        const float inv = 1.0f / l_i[i];
        const size_t row = (size_t)(b * T_SEQ + q0 + w * 16 + quad * 4 + i);
#pragma unroll
        for (int n = 0; n < 4; ++n)
            Y[row * CDIM + h * HD + n * 16 + ln] = f2bf(o[n][i] * inv);
    }
}

// ---------------------------------------------------------------------------
extern "C" void kernel_launch(void* const* d_in, const int* in_sizes, int n_in,
                              void* d_out, int out_size, void* d_ws, size_t ws_size,
                              hipStream_t stream)
{
    const float* X     = (const float*)d_in[0];
    const int*   mask  = (const int*)d_in[1];
    const float* Wqkv  = (const float*)d_in[2];
    const float* bqkv  = (const float*)d_in[3];
    const float* Wproj = (const float*)d_in[4];
    const float* bproj = (const float*)d_in[5];
    float* out = (float*)d_out;

    const size_t per = (size_t)2 * NHEAD * T_SEQ * HD;   // 4,194,304 elems
    unsigned short* Qp     = (unsigned short*)d_ws;
    unsigned short* Kp     = Qp + per;
    unsigned short* Vtp    = Kp + per;
    unsigned short* Xb     = Vtp + per;                  // aliased: Yp reuses Xb
    unsigned short* Yp     = Xb;                         // X consumed before Y written
    unsigned short* Wqkvt  = Xb + per;                   // [3072,1024]
    unsigned short* Wprojt = Wqkvt + (size_t)3 * CDIM * CDIM;  // [1024,1024]

    conv_bf16<<<2048, 256, 0, stream>>>(X, Xb, 4 * 1024 * 1024);
    transpose_conv<<<dim3(16, 48), 256, 0, stream>>>(Wqkv, Wqkvt, CDIM, 3 * CDIM);
    transpose_conv<<<dim3(16, 16), 256, 0, stream>>>(Wproj, Wprojt, CDIM, CDIM);

    qkv_gemm<<<dim3(32, 24), 256, 0, stream>>>(Xb, Wqkvt, bqkv, Qp, Kp, Vtp);
    flash_attn<<<dim3(T_SEQ / 64, 2 * NHEAD), 256, 0, stream>>>(Qp, Kp, Vtp, mask, Yp);
    proj_gemm<<<dim3(32, 8), 256, 0, stream>>>(Yp, Wprojt, bproj, out);
}

// Round 6
// 289.074 us; speedup vs baseline: 9.1689x; 1.0129x over previous
//
#include <hip/hip_runtime.h>

#define T_SEQ 2048
#define NHEAD 16
#define HD 64
#define CDIM 1024

typedef __bf16 bf16x8 __attribute__((ext_vector_type(8)));
typedef float f32x4 __attribute__((ext_vector_type(4)));

union U16x8 { uint4 u4; unsigned short s[8]; bf16x8 b; };

__device__ __forceinline__ float bf2f(unsigned short u) {
    return __uint_as_float(((unsigned int)u) << 16);
}
__device__ __forceinline__ unsigned short f2bf(float f) {
    unsigned int u = __float_as_uint(f);
    u += 0x7fffu + ((u >> 16) & 1u);   // round-to-nearest-even
    return (unsigned short)(u >> 16);
}
__device__ __forceinline__ U16x8 load8f(const float* __restrict__ p) {
    U16x8 r;
    float4 f0 = *(const float4*)p;
    float4 f1 = *(const float4*)(p + 4);
    r.s[0] = f2bf(f0.x); r.s[1] = f2bf(f0.y); r.s[2] = f2bf(f0.z); r.s[3] = f2bf(f0.w);
    r.s[4] = f2bf(f1.x); r.s[5] = f2bf(f1.y); r.s[6] = f2bf(f1.z); r.s[7] = f2bf(f1.w);
    return r;
}

// async global->LDS, 16 B per lane; LDS dest = wave-uniform base + lane*16
__device__ __forceinline__ void async_copy16(const unsigned short* g, unsigned short* l) {
    __builtin_amdgcn_global_load_lds(
        (const __attribute__((address_space(1))) unsigned int*)g,
        (__attribute__((address_space(3))) unsigned int*)l, 16, 0, 0);
}

// ---------------------------------------------------------------------------
// Conversion pass
// ---------------------------------------------------------------------------
__global__ __launch_bounds__(256) void conv_bf16(
    const float* __restrict__ in, unsigned short* __restrict__ out, int n)
{
    const int i = (blockIdx.x * 256 + threadIdx.x) * 8;
    if (i < n) {
        U16x8 o = load8f(&in[i]);
        *(uint4*)&out[i] = o.u4;
    }
}

// in: [R,C] fp32 -> out: [C,R] bf16.  R,C multiples of 64.
__global__ __launch_bounds__(256) void transpose_conv(
    const float* __restrict__ in, unsigned short* __restrict__ out, int R, int C)
{
    __shared__ float tile[64][65];
    const int r0 = blockIdx.x * 64;
    const int c0 = blockIdx.y * 64;
    const int tid = threadIdx.x;
    const int rr = tid >> 4;
    const int cc = (tid & 15) * 4;
#pragma unroll
    for (int p = 0; p < 4; ++p) {
        float4 v = *(const float4*)&in[(size_t)(r0 + p * 16 + rr) * C + c0 + cc];
        tile[p * 16 + rr][cc] = v.x;
        tile[p * 16 + rr][cc + 1] = v.y;
        tile[p * 16 + rr][cc + 2] = v.z;
        tile[p * 16 + rr][cc + 3] = v.w;
    }
    __syncthreads();
    const int n = tid >> 2;
    const int s = (tid & 3) * 8;
#pragma unroll
    for (int p = 0; p < 2; ++p) {
        const int k = s + p * 32;
        U16x8 o;
#pragma unroll
        for (int j = 0; j < 8; ++j) o.s[j] = f2bf(tile[k + j][n]);
        *(uint4*)&out[(size_t)(c0 + n) * R + r0 + k] = o.u4;
    }
}

// ---------------------------------------------------------------------------
// m97-style GEMM core: C[128x128] = A[M,K](bf16 rm) * Bt[N,K](bf16 rm)^T
// 256 threads = 4 waves in 2x2; BK=64; global_load_lds 16B staging; 4x4 acc.
// ---------------------------------------------------------------------------
__device__ __forceinline__ void gemm128_core(
    const unsigned short* __restrict__ A,
    const unsigned short* __restrict__ Bt,
    int K, int m0, int n0,
    unsigned short* As, unsigned short* Bs, f32x4 acc[4][4])
{
    const int tid = threadIdx.x;
    const int w = tid >> 6, lane = tid & 63;
    const int ln = lane & 15, quad = lane >> 4;
    const int wm = w >> 1, wn = w & 1;
    const int lr = lane >> 3;        // 0..7
    const int lc = (lane & 7) * 8;   // col start (elems)

    for (int kb = 0; kb < K; kb += 64) {
        __syncthreads();
#pragma unroll
        for (int i = 0; i < 4; ++i) {
            async_copy16(&A[(size_t)(m0 + w * 32 + i * 8 + lr) * K + kb + lc],
                         &As[(w * 32 + i * 8) * 64]);
            async_copy16(&Bt[(size_t)(n0 + w * 32 + i * 8 + lr) * K + kb + lc],
                         &Bs[(w * 32 + i * 8) * 64]);
        }
        __syncthreads();
#pragma unroll
        for (int kk = 0; kk < 2; ++kk) {
            U16x8 af[4], bff[4];
#pragma unroll
            for (int i = 0; i < 4; ++i)
                af[i].u4 = *(const uint4*)&As[(wm * 64 + i * 16 + ln) * 64 + kk * 32 + quad * 8];
#pragma unroll
            for (int j = 0; j < 4; ++j)
                bff[j].u4 = *(const uint4*)&Bs[(wn * 64 + j * 16 + ln) * 64 + kk * 32 + quad * 8];
#pragma unroll
            for (int i = 0; i < 4; ++i)
#pragma unroll
                for (int j = 0; j < 4; ++j)
                    acc[i][j] = __builtin_amdgcn_mfma_f32_16x16x32_bf16(af[i].b, bff[j].b, acc[i][j], 0, 0, 0);
        }
    }
}

// ---------------------------------------------------------------------------
// Kernel: QKV GEMM + scatter.  Q,K -> [B,H,T,hd]; V -> [B,H,hd,T]
// ---------------------------------------------------------------------------
__global__ __launch_bounds__(256) void qkv_gemm(
    const unsigned short* __restrict__ Xb,    // [4096,1024] bf16
    const unsigned short* __restrict__ Wt,    // [3072,1024] bf16 (W^T)
    const float* __restrict__ bias,           // [3072]
    unsigned short* __restrict__ Qp,
    unsigned short* __restrict__ Kp,
    unsigned short* __restrict__ Vtp)
{
    __shared__ unsigned short As[128 * 64];
    __shared__ unsigned short Bs[128 * 64];
    const int m0 = blockIdx.x * 128;
    const int n0 = blockIdx.y * 128;

    f32x4 acc[4][4];
#pragma unroll
    for (int i = 0; i < 4; ++i)
#pragma unroll
        for (int j = 0; j < 4; ++j) acc[i][j] = (f32x4){0.f, 0.f, 0.f, 0.f};

    gemm128_core(Xb, Wt, CDIM, m0, n0, As, Bs, acc);

    const int tid = threadIdx.x;
    const int w = tid >> 6, lane = tid & 63;
    const int ln = lane & 15, quad = lane >> 4;
    const int wm = w >> 1, wn = w & 1;

#pragma unroll
    for (int j = 0; j < 4; ++j) {
        const int n = n0 + wn * 64 + j * 16 + ln;
        const float bv = bias[n];
        const int which = n >> 10;
        const int h = (n >> 6) & 15, d = n & 63;
#pragma unroll
        for (int i = 0; i < 4; ++i)
#pragma unroll
            for (int r = 0; r < 4; ++r) {
                const int m = m0 + wm * 64 + i * 16 + quad * 4 + r;
                const int b = m >> 11, tt = m & 2047;
                const unsigned short val = f2bf(acc[i][j][r] + bv);
                if (which == 0)
                    Qp[(((b * NHEAD + h) * T_SEQ) + tt) * HD + d] = val;
                else if (which == 1)
                    Kp[(((b * NHEAD + h) * T_SEQ) + tt) * HD + d] = val;
                else
                    Vtp[(((b * NHEAD + h) * HD) + d) * T_SEQ + tt] = val;
            }
    }
}

// ---------------------------------------------------------------------------
// Kernel: proj GEMM -> fp32 out
// ---------------------------------------------------------------------------
__global__ __launch_bounds__(256) void proj_gemm(
    const unsigned short* __restrict__ Yin,   // [4096,1024] bf16
    const unsigned short* __restrict__ Wt,    // [1024,1024] bf16 (W^T)
    const float* __restrict__ bias,           // [1024]
    float* __restrict__ out)                  // [4096,1024] fp32
{
    __shared__ unsigned short As[128 * 64];
    __shared__ unsigned short Bs[128 * 64];
    const int m0 = blockIdx.x * 128;
    const int n0 = blockIdx.y * 128;

    f32x4 acc[4][4];
#pragma unroll
    for (int i = 0; i < 4; ++i)
#pragma unroll
        for (int j = 0; j < 4; ++j) acc[i][j] = (f32x4){0.f, 0.f, 0.f, 0.f};

    gemm128_core(Yin, Wt, CDIM, m0, n0, As, Bs, acc);

    const int tid = threadIdx.x;
    const int w = tid >> 6, lane = tid & 63;
    const int ln = lane & 15, quad = lane >> 4;
    const int wm = w >> 1, wn = w & 1;

#pragma unroll
    for (int j = 0; j < 4; ++j) {
        const int n = n0 + wn * 64 + j * 16 + ln;
        const float bv = bias[n];
#pragma unroll
        for (int i = 0; i < 4; ++i)
#pragma unroll
            for (int r = 0; r < 4; ++r) {
                const int m = m0 + wm * 64 + i * 16 + quad * 4 + r;
                out[(size_t)m * CDIM + n] = acc[i][j][r] + bv;
            }
    }
}

// ---------------------------------------------------------------------------
// MFMA flash attention with register-prefetch double buffering:
// issue tile j+1's K/V global loads right after the compute barrier, compute
// tile j from LDS, wait on loads only at next iteration's LDS write.
// ---------------------------------------------------------------------------
#define ATT_STRIDE 72

__global__ __launch_bounds__(256) void flash_attn(
    const unsigned short* __restrict__ Qp,   // [BH, T, 64]
    const unsigned short* __restrict__ Kp,   // [BH, T, 64]
    const unsigned short* __restrict__ Vtp,  // [BH, 64, T]
    const int* __restrict__ mask,            // [B, T]
    unsigned short* __restrict__ Y)          // [B*T, 1024] bf16
{
    __shared__ unsigned short Ks[64 * ATT_STRIDE];
    __shared__ unsigned short Vs[64 * ATT_STRIDE];
    __shared__ unsigned short Ps[64 * ATT_STRIDE];
    __shared__ int mask_s[64];

    const int qt = gridDim.x - 1 - blockIdx.x;   // heavy tiles launch first
    const int bh = blockIdx.y;
    const int b = bh >> 4, h = bh & 15;
    const int tid = threadIdx.x;
    const int w = tid >> 6, lane = tid & 63;
    const int ln = lane & 15, quad = lane >> 4;
    const int row8 = tid >> 3, seg = tid & 7;
    const size_t base = (size_t)bh * T_SEQ * HD;
    const int q0 = qt * 64;

    U16x8 qf[2];
    {
        const unsigned short* qrow = &Qp[base + (size_t)(q0 + w * 16 + ln) * HD];
        qf[0].u4 = *(const uint4*)&qrow[quad * 8];
        qf[1].u4 = *(const uint4*)&qrow[32 + quad * 8];
    }

    f32x4 o[4];
#pragma unroll
    for (int n = 0; n < 4; ++n) o[n] = (f32x4){0.f, 0.f, 0.f, 0.f};
    float m_i[4] = {-3.0e38f, -3.0e38f, -3.0e38f, -3.0e38f};
    float l_i[4] = {0.f, 0.f, 0.f, 0.f};

    // register prefetch state for tile j
    uint4 kr0, kr1, vr0, vr1;
    int mreg = 0;
    {
        const unsigned short* kp0 = &Kp[base + (size_t)row8 * HD + seg * 8];
        kr0 = *(const uint4*)kp0;
        kr1 = *(const uint4*)(kp0 + 32 * HD);
        const unsigned short* vp0 = &Vtp[base + (size_t)row8 * T_SEQ + seg * 8];
        vr0 = *(const uint4*)vp0;
        vr1 = *(const uint4*)(vp0 + 32 * T_SEQ);
        if (tid < 64) mreg = mask[b * T_SEQ + tid];
    }

    for (int j = 0; j <= qt; ++j) {
        __syncthreads();   // previous iteration's LDS reads complete
        // drain prefetched tile j into LDS
        *(uint4*)&Ks[row8 * ATT_STRIDE + seg * 8] = kr0;
        *(uint4*)&Ks[(row8 + 32) * ATT_STRIDE + seg * 8] = kr1;
        *(uint4*)&Vs[row8 * ATT_STRIDE + seg * 8] = vr0;
        *(uint4*)&Vs[(row8 + 32) * ATT_STRIDE + seg * 8] = vr1;
        if (tid < 64) mask_s[tid] = mreg;
        __syncthreads();

        // issue tile j+1 loads (latency hidden behind compute below)
        if (j < qt) {
            const unsigned short* kp0 = &Kp[base + (size_t)((j + 1) * 64 + row8) * HD + seg * 8];
            kr0 = *(const uint4*)kp0;
            kr1 = *(const uint4*)(kp0 + 32 * HD);
            const unsigned short* vp0 = &Vtp[base + (size_t)row8 * T_SEQ + (j + 1) * 64 + seg * 8];
            vr0 = *(const uint4*)vp0;
            vr1 = *(const uint4*)(vp0 + 32 * T_SEQ);
            if (tid < 64) mreg = mask[b * T_SEQ + (j + 1) * 64 + tid];
        }

        const bool diag = (j == qt);

        f32x4 sc[4];
#pragma unroll
        for (int t = 0; t < 4; ++t) sc[t] = (f32x4){0.f, 0.f, 0.f, 0.f};
#pragma unroll
        for (int t = 0; t < 4; ++t) {
            if (diag && t > w) continue;
#pragma unroll
            for (int s = 0; s < 2; ++s) {
                U16x8 kb;
                kb.u4 = *(const uint4*)&Ks[(t * 16 + ln) * ATT_STRIDE + s * 32 + quad * 8];
                sc[t] = __builtin_amdgcn_mfma_f32_16x16x32_bf16(qf[s].b, kb.b, sc[t], 0, 0, 0);
            }
        }

        float rm[4] = {-3.0e38f, -3.0e38f, -3.0e38f, -3.0e38f};
#pragma unroll
        for (int t = 0; t < 4; ++t) {
            const int pad = mask_s[t * 16 + ln];
            const bool allmask = diag && (t > w);
            const bool edge = diag && (t == w);
#pragma unroll
            for (int i = 0; i < 4; ++i) {
                float v = sc[t][i] * 0.125f;
                if (pad == 0 || allmask || (edge && ln > quad * 4 + i)) v = -1.0e30f;
                sc[t][i] = v;
                rm[i] = fmaxf(rm[i], v);
            }
        }
#pragma unroll
        for (int i = 0; i < 4; ++i) {
            rm[i] = fmaxf(rm[i], __shfl_xor(rm[i], 1));
            rm[i] = fmaxf(rm[i], __shfl_xor(rm[i], 2));
            rm[i] = fmaxf(rm[i], __shfl_xor(rm[i], 4));
            rm[i] = fmaxf(rm[i], __shfl_xor(rm[i], 8));
        }

        float alpha[4], rs[4] = {0.f, 0.f, 0.f, 0.f};
#pragma unroll
        for (int i = 0; i < 4; ++i) {
            const float nm = fmaxf(m_i[i], rm[i]);
            alpha[i] = __expf(m_i[i] - nm);
            m_i[i] = nm;
        }
#pragma unroll
        for (int t = 0; t < 4; ++t)
#pragma unroll
            for (int i = 0; i < 4; ++i) {
                const float p = __expf(sc[t][i] - m_i[i]);
                sc[t][i] = p;
                rs[i] += p;
            }
#pragma unroll
        for (int i = 0; i < 4; ++i) {
            rs[i] += __shfl_xor(rs[i], 1);
            rs[i] += __shfl_xor(rs[i], 2);
            rs[i] += __shfl_xor(rs[i], 4);
            rs[i] += __shfl_xor(rs[i], 8);
            l_i[i] = l_i[i] * alpha[i] + rs[i];
        }
#pragma unroll
        for (int n = 0; n < 4; ++n)
#pragma unroll
            for (int i = 0; i < 4; ++i) o[n][i] *= alpha[i];

#pragma unroll
        for (int t = 0; t < 4; ++t)
#pragma unroll
            for (int i = 0; i < 4; ++i)
                Ps[(w * 16 + quad * 4 + i) * ATT_STRIDE + t * 16 + ln] = f2bf(sc[t][i]);

        U16x8 pa[2];
        pa[0].u4 = *(const uint4*)&Ps[(w * 16 + ln) * ATT_STRIDE + quad * 8];
        pa[1].u4 = *(const uint4*)&Ps[(w * 16 + ln) * ATT_STRIDE + 32 + quad * 8];

#pragma unroll
        for (int n = 0; n < 4; ++n)
#pragma unroll
            for (int s = 0; s < 2; ++s) {
                U16x8 vb;
                vb.u4 = *(const uint4*)&Vs[(n * 16 + ln) * ATT_STRIDE + s * 32 + quad * 8];
                o[n] = __builtin_amdgcn_mfma_f32_16x16x32_bf16(pa[s].b, vb.b, o[n], 0, 0, 0);
            }
    }

#pragma unroll
    for (int i = 0; i < 4; ++i) {
        const float inv = 1.0f / l_i[i];
        const size_t row = (size_t)(b * T_SEQ + q0 + w * 16 + quad * 4 + i);
#pragma unroll
        for (int n = 0; n < 4; ++n)
            Y[row * CDIM + h * HD + n * 16 + ln] = f2bf(o[n][i] * inv);
    }
}

// ---------------------------------------------------------------------------
extern "C" void kernel_launch(void* const* d_in, const int* in_sizes, int n_in,
                              void* d_out, int out_size, void* d_ws, size_t ws_size,
                              hipStream_t stream)
{
    const float* X     = (const float*)d_in[0];
    const int*   mask  = (const int*)d_in[1];
    const float* Wqkv  = (const float*)d_in[2];
    const float* bqkv  = (const float*)d_in[3];
    const float* Wproj = (const float*)d_in[4];
    const float* bproj = (const float*)d_in[5];
    float* out = (float*)d_out;

    const size_t per = (size_t)2 * NHEAD * T_SEQ * HD;   // 4,194,304 elems
    unsigned short* Qp     = (unsigned short*)d_ws;
    unsigned short* Kp     = Qp + per;
    unsigned short* Vtp    = Kp + per;
    unsigned short* Xb     = Vtp + per;                  // aliased: Yp reuses Xb
    unsigned short* Yp     = Xb;                         // X consumed before Y written
    unsigned short* Wqkvt  = Xb + per;                   // [3072,1024]
    unsigned short* Wprojt = Wqkvt + (size_t)3 * CDIM * CDIM;  // [1024,1024]

    conv_bf16<<<2048, 256, 0, stream>>>(X, Xb, 4 * 1024 * 1024);
    transpose_conv<<<dim3(16, 48), 256, 0, stream>>>(Wqkv, Wqkvt, CDIM, 3 * CDIM);
    transpose_conv<<<dim3(16, 16), 256, 0, stream>>>(Wproj, Wprojt, CDIM, CDIM);

    qkv_gemm<<<dim3(32, 24), 256, 0, stream>>>(Xb, Wqkvt, bqkv, Qp, Kp, Vtp);
    flash_attn<<<dim3(T_SEQ / 64, 2 * NHEAD), 256, 0, stream>>>(Qp, Kp, Vtp, mask, Yp);
    proj_gemm<<<dim3(32, 8), 256, 0, stream>>>(Yp, Wprojt, bproj, out);
}